// Round 6
// baseline (289.013 us; speedup 1.0000x reference)
//
#include <hip/hip_runtime.h>
#include <cstdint>
#include <cstddef>

#define D_IN   256
#define D_OUT  128
#define NB_MAX 256   // row buckets = (n+255)>>8 ; requires n <= 65535 (row/col in 16 bits)
#define NPASS  4
#define SEGW   32    // cols per pass

typedef short bf16x8 __attribute__((ext_vector_type(8)));
typedef float f32x4  __attribute__((ext_vector_type(4)));

union Frag { bf16x8 v; uint32_t u[4]; };

struct Branch {
  const float* X;
  const int*   idx;
  const float* val;
  uint16_t* H;          // 4 planes of [n][32] bf16 (col-segmented)
  int*   ptr;           // n+1
  int*   bucketTotal;   // NB_MAX
  int*   bucketBase;    // NB_MAX+1
  int*   bucketCur;     // NB_MAX
  uint64_t* kv2;        // ne: bucket-grouped (val32 | row16 | col16)
  uint32_t* csr4;       // ne: (val_bf16<<16 | col)
  float* out;
};

__device__ inline uint32_t cvt_pk_bf16(float lo, float hi) {
  uint32_t r;
  asm("v_cvt_pk_bf16_f32 %0, %1, %2" : "=v"(r) : "v"(lo), "v"(hi));
  return r;
}

// exclusive prefix over 256 threads (4 waves)
__device__ inline int block_scan256_excl(int v, int tid) {
  int lane = tid & 63, w = tid >> 6;
  int s = v;
  #pragma unroll
  for (int off = 1; off < 64; off <<= 1) {
    int t = __shfl_up(s, off);
    if (lane >= off) s += t;
  }
  __shared__ int wsum[4];
  if (lane == 63) wsum[w] = s;
  __syncthreads();
  int add = 0;
  #pragma unroll
  for (int i = 0; i < 4; ++i) add += (i < w) ? wsum[i] : 0;
  return s + add - v;
}

// ---------------- W prep: W[256][128] fp32 -> W^T[128][256] bf16 (RNE) ----------------
__global__ __launch_bounds__(256) void wprep_kernel(const float* __restrict__ W,
                                                    uint16_t* __restrict__ WT) {
  int n = blockIdx.x;    // 0..127
  int k = threadIdx.x;   // 0..255
  uint32_t u = __float_as_uint(W[k * 128 + n]);
  WT[n * 256 + k] = (uint16_t)((u + 0x7FFFu + ((u >> 16) & 1u)) >> 16);
}

// ---------------- GEMM: H = X @ W  (bf16 MFMA, fp32 acc, bf16 col-segmented store) ----------------
__global__ __launch_bounds__(256, 2) void gemm_mfma_kernel(const uint16_t* __restrict__ WT,
                                                           Branch b0, Branch b1, int n_rows) {
  Branch b = blockIdx.y ? b1 : b0;
  const int tid = threadIdx.x;
  const int w = tid >> 6;
  const int l = tid & 63;
  const int c = l & 15;
  const int g = l >> 4;
  const int row0 = blockIdx.x * 128 + w * 32;

  __shared__ uint16_t sStg[4][32][136];

  f32x4 acc[2][8];
  #pragma unroll
  for (int i = 0; i < 2; ++i)
    #pragma unroll
    for (int j = 0; j < 8; ++j) acc[i][j] = (f32x4){0.f, 0.f, 0.f, 0.f};

  int r0 = row0 + c;      if (r0 > n_rows - 1) r0 = n_rows - 1;
  int r1 = row0 + 16 + c; if (r1 > n_rows - 1) r1 = n_rows - 1;
  const float4* X0 = (const float4*)(b.X + (size_t)r0 * D_IN);
  const float4* X1 = (const float4*)(b.X + (size_t)r1 * D_IN);

  #pragma unroll
  for (int ks = 0; ks < 8; ++ks) {
    const int k4 = ks * 8;
    float4 a0 = X0[k4 + g], a0b = X0[k4 + 4 + g];
    float4 a1 = X1[k4 + g], a1b = X1[k4 + 4 + g];
    Frag A0, A1;
    A0.u[0] = cvt_pk_bf16(a0.x, a0.y);   A0.u[1] = cvt_pk_bf16(a0.z, a0.w);
    A0.u[2] = cvt_pk_bf16(a0b.x, a0b.y); A0.u[3] = cvt_pk_bf16(a0b.z, a0b.w);
    A1.u[0] = cvt_pk_bf16(a1.x, a1.y);   A1.u[1] = cvt_pk_bf16(a1.z, a1.w);
    A1.u[2] = cvt_pk_bf16(a1b.x, a1b.y); A1.u[3] = cvt_pk_bf16(a1b.z, a1b.w);
    #pragma unroll
    for (int nf = 0; nf < 8; ++nf) {
      const uint2* Wp = (const uint2*)(WT + ((size_t)(nf * 16 + c) << 8));
      uint2 wa = Wp[k4 + g];
      uint2 wb = Wp[k4 + 4 + g];
      Frag B;
      B.u[0] = wa.x; B.u[1] = wa.y; B.u[2] = wb.x; B.u[3] = wb.y;
      acc[0][nf] = __builtin_amdgcn_mfma_f32_16x16x32_bf16(A0.v, B.v, acc[0][nf], 0, 0, 0);
      acc[1][nf] = __builtin_amdgcn_mfma_f32_16x16x32_bf16(A1.v, B.v, acc[1][nf], 0, 0, 0);
    }
  }

  // epilogue: pair cols via shfl_xor(1), pack bf16x2, stage in LDS
  #pragma unroll
  for (int rf = 0; rf < 2; ++rf)
    #pragma unroll
    for (int nf = 0; nf < 8; ++nf)
      #pragma unroll
      for (int r = 0; r < 4; ++r) {
        float v = acc[rf][nf][r];
        float o = __shfl_xor(v, 1);
        if (!(l & 1)) {
          uint32_t pk = cvt_pk_bf16(v, o);
          int rowl = rf * 16 + g * 4 + r;
          int col  = nf * 16 + c;
          *(uint32_t*)&sStg[w][rowl][col] = pk;
        }
      }
  __syncthreads();
  // write 4 col-segment planes: 4 lanes per row (seg = l&3), 16 rows per step
  #pragma unroll
  for (int half = 0; half < 2; ++half) {
    int rl  = half * 16 + (l >> 2);
    int seg = l & 3;
    int row_g = row0 + rl;
    if (row_g < n_rows) {
      uint16_t* dst = b.H + (size_t)seg * n_rows * SEGW + (size_t)row_g * SEGW;
      #pragma unroll
      for (int i = 0; i < 4; ++i)
        *(uint4*)(dst + i * 8) = *(const uint4*)&sStg[w][rl][seg * SEGW + i * 8];
    }
  }
}

// ---------------- bucket-level counting ----------------
__global__ __launch_bounds__(256) void bucket_count_kernel(Branch b0, Branch b1, int ne, int nb) {
  Branch b = blockIdx.y ? b1 : b0;
  __shared__ int hist[NB_MAX];
  const int tid = threadIdx.x;
  const int base = blockIdx.x * 4096;
  if (tid < nb) hist[tid] = 0;
  __syncthreads();
  #pragma unroll
  for (int i = 0; i < 16; ++i) {
    int e = base + i * 256 + tid;
    if (e < ne) {
      int r = ((const int2*)b.idx)[e].x;
      atomicAdd(&hist[r >> 8], 1);
    }
  }
  __syncthreads();
  if (tid < nb) {
    int h = hist[tid];
    if (h) atomicAdd(&b.bucketTotal[tid], h);
  }
}

__global__ __launch_bounds__(256) void bucket_scan_kernel(Branch b0, Branch b1, int nb, int n, int ne) {
  Branch b = blockIdx.y ? b1 : b0;
  const int tid = threadIdx.x;
  int v = (tid < nb) ? b.bucketTotal[tid] : 0;
  int excl = block_scan256_excl(v, tid);
  if (tid <= nb) b.bucketBase[tid] = excl;
  if (tid < nb)  b.bucketCur[tid]  = excl;
  if (tid == 0)  b.ptr[n] = ne;
}

// ---------------- bin: bucket-grouped scatter ----------------
__global__ __launch_bounds__(256) void bin_kernel(Branch b0, Branch b1, int ne, int nb) {
  Branch b = blockIdx.y ? b1 : b0;
  __shared__ int hist[NB_MAX];
  __shared__ int lcur[NB_MAX];
  __shared__ int gbase[NB_MAX];
  const int tid = threadIdx.x;
  const int base = blockIdx.x * 4096;
  if (tid < nb) hist[tid] = 0;
  __syncthreads();
  uint64_t kv2[16];
  int bkt[16];
  #pragma unroll
  for (int i = 0; i < 16; ++i) {
    int e = base + i * 256 + tid;
    bkt[i] = -1;
    if (e < ne) {
      int2 rc = ((const int2*)b.idx)[e];
      uint32_t v = __float_as_uint(b.val[e]);
      kv2[i] = ((uint64_t)v << 32) | ((uint32_t)rc.x << 16) | (uint32_t)rc.y;
      bkt[i] = rc.x >> 8;
      atomicAdd(&hist[bkt[i]], 1);
    }
  }
  __syncthreads();
  if (tid < nb) {
    int h = hist[tid];
    gbase[tid] = h ? atomicAdd(&b.bucketCur[tid], h) : 0;
    lcur[tid] = 0;
  }
  __syncthreads();
  #pragma unroll
  for (int i = 0; i < 16; ++i) {
    if (bkt[i] >= 0) {
      int dst = gbase[bkt[i]] + atomicAdd(&lcur[bkt[i]], 1);
      b.kv2[dst] = kv2[i];
    }
  }
}

// ---------------- per-bucket CSR finalize: 4B entries (val_bf16<<16 | col) ----------------
__global__ __launch_bounds__(256) void bucket_csr_kernel(Branch b0, Branch b1, int n) {
  Branch b = blockIdx.y ? b1 : b0;
  const int bkt = blockIdx.x;
  const int tid = threadIdx.x;
  const int beg = b.bucketBase[bkt], end = b.bucketBase[bkt + 1];
  __shared__ int hist[256];
  __shared__ int cur[256];
  hist[tid] = 0;
  __syncthreads();
  for (int e = beg + tid; e < end; e += 256)
    atomicAdd(&hist[(int)((b.kv2[e] >> 16) & 0xFF)], 1);
  __syncthreads();
  int v = hist[tid];
  int excl = block_scan256_excl(v, tid);
  cur[tid] = beg + excl;
  int row = bkt * 256 + tid;
  if (row < n) b.ptr[row] = beg + excl;
  __syncthreads();
  for (int e = beg + tid; e < end; e += 256) {
    uint64_t kv2 = b.kv2[e];
    int r = (int)((kv2 >> 16) & 0xFF);
    uint32_t u = (uint32_t)(kv2 >> 32);
    uint32_t vbf = (u + 0x7FFFu + ((u >> 16) & 1u)) & 0xFFFF0000u;  // RNE bf16 in high16
    int pos = atomicAdd(&cur[r], 1);
    b.csr4[pos] = vbf | (uint32_t)(kv2 & 0xFFFFu);
  }
}

// ---------------- per-row gather + relu, one col-segment per launch ----------------
// linear grid; XCD routing: branch = ((bid & 7) >> 2)  [XCD = bid % 8]
__global__ __launch_bounds__(256) void gather_pass_kernel(Branch b0, Branch b1, int n_rows,
                                                          int pass) {
  const int bid = blockIdx.x;
  const int br  = (bid & 7) >> 2;
  const int local = (bid >> 3) * 4 + (bid & 3);
  Branch b = br ? b1 : b0;
  const int tid = threadIdx.x;
  const int lane8 = tid & 7;
  const int row = local * 32 + (tid >> 3);
  if (row >= n_rows) return;

  const uint16_t* Hp = b.H + (size_t)pass * n_rows * SEGW;
  int beg = b.ptr[row], end = b.ptr[row + 1];
  float4 acc = make_float4(0.f, 0.f, 0.f, 0.f);

  auto fma_edge = [&](uint32_t e4) {
    int c = (int)(e4 & 0xFFFFu);
    float v = __uint_as_float(e4 & 0xFFFF0000u);   // bf16 val in high bits
    uint2 h = *(const uint2*)(Hp + (size_t)c * SEGW + lane8 * 4);
    float h0 = __uint_as_float(h.x << 16);
    float h1 = __uint_as_float(h.x & 0xFFFF0000u);
    float h2 = __uint_as_float(h.y << 16);
    float h3 = __uint_as_float(h.y & 0xFFFF0000u);
    acc.x = fmaf(h0, v, acc.x); acc.y = fmaf(h1, v, acc.y);
    acc.z = fmaf(h2, v, acc.z); acc.w = fmaf(h3, v, acc.w);
  };

  int e = beg;
  for (; e + 4 <= end; e += 4) {
    uint32_t kA = b.csr4[e + 0], kB = b.csr4[e + 1];
    uint32_t kC = b.csr4[e + 2], kD = b.csr4[e + 3];
    fma_edge(kA); fma_edge(kB); fma_edge(kC); fma_edge(kD);
  }
  for (; e < end; ++e) fma_edge(b.csr4[e]);

  float4 o;
  o.x = fmaxf(acc.x, 0.f); o.y = fmaxf(acc.y, 0.f);
  o.z = fmaxf(acc.z, 0.f); o.w = fmaxf(acc.w, 0.f);
  *(float4*)&b.out[(size_t)row * D_OUT + pass * SEGW + lane8 * 4] = o;
}

extern "C" void kernel_launch(void* const* d_in, const int* in_sizes, int n_in,
                              void* d_out, int out_size, void* d_ws, size_t ws_size,
                              hipStream_t stream) {
  const float* inp_s = (const float*)d_in[0];
  const float* inp_t = (const float*)d_in[1];
  const int*   idx_s = (const int*)d_in[2];
  const float* val_s = (const float*)d_in[3];
  const int*   idx_t = (const int*)d_in[4];
  const float* val_t = (const float*)d_in[5];
  const float* W     = (const float*)d_in[6];
  float* out = (float*)d_out;

  const int n  = in_sizes[0] / D_IN;   // 50000
  const int ne = in_sizes[3];          // 1600000
  const int nb = (n + 255) >> 8;       // 196

  char* p = (char*)d_ws;
  auto alloc = [&](size_t bytes) -> char* {
    char* r = p;
    p += (bytes + 255) & ~(size_t)255;
    return r;
  };
  uint16_t* H_s    = (uint16_t*)alloc((size_t)n * D_OUT * 2);
  uint16_t* H_t    = (uint16_t*)alloc((size_t)n * D_OUT * 2);
  uint16_t* WT     = (uint16_t*)alloc((size_t)128 * 256 * 2);
  int* ptr_s       = (int*)alloc((size_t)(n + 1) * 4);
  int* ptr_t       = (int*)alloc((size_t)(n + 1) * 4);
  int* btotal      = (int*)alloc((size_t)2 * NB_MAX * 4);
  int* btotal_s    = btotal;
  int* btotal_t    = btotal + NB_MAX;
  int* bbase_s     = (int*)alloc((size_t)(NB_MAX + 1) * 4);
  int* bbase_t     = (int*)alloc((size_t)(NB_MAX + 1) * 4);
  int* bcur_s      = (int*)alloc(NB_MAX * 4);
  int* bcur_t      = (int*)alloc(NB_MAX * 4);
  uint64_t* kv2_s  = (uint64_t*)alloc((size_t)ne * 8);
  uint64_t* kv2_t  = (uint64_t*)alloc((size_t)ne * 8);
  uint32_t* c4_s   = (uint32_t*)alloc((size_t)ne * 4);
  uint32_t* c4_t   = (uint32_t*)alloc((size_t)ne * 4);

  Branch bs = { inp_s, idx_s, val_s, H_s, ptr_s, btotal_s, bbase_s, bcur_s, kv2_s, c4_s, out };
  Branch bt = { inp_t, idx_t, val_t, H_t, ptr_t, btotal_t, bbase_t, bcur_t, kv2_t, c4_t,
                out + (size_t)n * D_OUT };

  const int nblkE = (ne + 4095) / 4096;
  const int bpb   = (((n + 31) / 32) + 3) & ~3;   // blocks per branch, %4==0

  hipMemsetAsync(btotal, 0, (size_t)2 * NB_MAX * 4, stream);
  wprep_kernel<<<dim3(128), 256, 0, stream>>>(W, WT);
  gemm_mfma_kernel<<<dim3((n + 127) / 128, 2), 256, 0, stream>>>(WT, bs, bt, n);
  bucket_count_kernel<<<dim3(nblkE, 2), 256, 0, stream>>>(bs, bt, ne, nb);
  bucket_scan_kernel<<<dim3(1, 2), 256, 0, stream>>>(bs, bt, nb, n, ne);
  bin_kernel<<<dim3(nblkE, 2), 256, 0, stream>>>(bs, bt, ne, nb);
  bucket_csr_kernel<<<dim3(nb, 2), 256, 0, stream>>>(bs, bt, n);
  for (int pass = 0; pass < NPASS; ++pass)
    gather_pass_kernel<<<dim3(2 * bpb), 256, 0, stream>>>(bs, bt, n, pass);
}